// Round 1
// 262.676 us; speedup vs baseline: 1.0196x; 1.0196x over previous
//
#include <hip/hip_runtime.h>

// Problem constants
#define Bc 2
#define Sc 1024
#define Dc 1024
#define Hc 2048
#define Ec 8
#define Kc 2
#define Tc (Bc*Sc)      // 2048 tokens
#define Pc (Tc*Kc)      // 4096 jobs
#define PADROWS 128     // tile-overrun padding for Xg / hidden
#define MAXTILES 40     // sum_e ceil(cnt_e/128) <= 4096/128 + 8 = 40

typedef __bf16 bf16x8 __attribute__((ext_vector_type(8)));
typedef float floatx4 __attribute__((ext_vector_type(4)));
typedef unsigned short ushort4_t __attribute__((ext_vector_type(4)));

__device__ inline unsigned short f2bf(float f) {
    unsigned u = __builtin_bit_cast(unsigned, f);
    unsigned r = u + 0x7fffu + ((u >> 16) & 1u);   // RNE
    return (unsigned short)(r >> 16);
}

// flax nn.gelu approximate=True: 0.5v(1+tanh(y)) == v * sigmoid(2y)
__device__ inline float gelu_fast(float v) {
    float z = 1.5957691216057308f * (v + 0.044715f * v * v * v);  // 2y
    return v / (1.0f + __expf(-z));
}

// async global->LDS, 16B per lane; LDS dest = wave-uniform base + lane*16
__device__ inline void gload_lds16(const void* g, void* l) {
    __builtin_amdgcn_global_load_lds((const __attribute__((address_space(1))) unsigned int*)g,
                                     (__attribute__((address_space(3))) unsigned int*)l,
                                     16, 0, 0);
}

// ---------- single-block bucketing: counts + prefix + tile list + job fill ----------
__global__ void bucket_kernel(const int* __restrict__ idx, const float* __restrict__ wts,
                              int* __restrict__ counts, int* __restrict__ offs,
                              int* __restrict__ tile_e, int* __restrict__ tile_m0,
                              int* __restrict__ n_tiles,
                              int* __restrict__ job_token, float* __restrict__ job_w) {
    __shared__ int lc[Ec], lf[Ec], lo[Ec];
    int t = threadIdx.x;
    if (t < Ec) { lc[t] = 0; lf[t] = 0; }
    __syncthreads();
    int myid[Pc / 256];
#pragma unroll
    for (int j = 0; j < Pc / 256; j++) {
        int i = t + j * 256;
        myid[j] = idx[i];
        atomicAdd(&lc[myid[j]], 1);
    }
    __syncthreads();
    if (t == 0) {
        int s = 0, tt = 0;
        for (int e = 0; e < Ec; e++) {
            lo[e] = s; offs[e] = s; counts[e] = lc[e];
            for (int m0 = 0; m0 < lc[e]; m0 += 128) { tile_e[tt] = e; tile_m0[tt] = m0; tt++; }
            s += lc[e];
        }
        offs[Ec] = s;
        *n_tiles = tt;
    }
    __syncthreads();
#pragma unroll
    for (int j = 0; j < Pc / 256; j++) {
        int i = t + j * 256;
        int e = myid[j];
        int pos = lo[e] + atomicAdd(&lf[e], 1);
        job_token[pos] = i >> 1;          // i = token*K + k
        job_w[pos] = wts[i];
    }
}

// ---------- fused: fp32->bf16 weight convert (unit-stride) + x-row gather ----------
// blocks [0, 2048)        : convert keys   (2048 float4 per block, 8 passes)
// blocks [2048, 4096)     : convert values
// blocks [4096, 4096+Pc)  : gather one x row -> Xg
#define CONV_BLOCKS 4096
#define PREP_BLOCKS (CONV_BLOCKS + Pc)
__global__ __launch_bounds__(256) void prep_kernel(
    const float* __restrict__ keys, const float* __restrict__ values,
    unsigned short* __restrict__ keysb, unsigned short* __restrict__ valsb,
    const float* __restrict__ x, const int* __restrict__ job_token,
    unsigned short* __restrict__ Xg)
{
    int b = blockIdx.x, t = threadIdx.x;
    if (b < CONV_BLOCKS) {
        const float* s; unsigned short* d; int tb;
        if (b < CONV_BLOCKS / 2) { s = keys;   d = keysb; tb = b; }
        else                     { s = values; d = valsb; tb = b - CONV_BLOCKS / 2; }
        size_t base = (size_t)tb * 2048;     // float4 units
#pragma unroll
        for (int p = 0; p < 8; p++) {
            size_t i = base + (size_t)p * 256 + t;      // unit-stride across lanes
            float4 v = ((const float4*)s)[i];
            ushort4_t o = { f2bf(v.x), f2bf(v.y), f2bf(v.z), f2bf(v.w) };
            ((ushort4_t*)d)[i] = o;
        }
    } else {
        int row = b - CONV_BLOCKS;
        int tok = job_token[row];
        float4 v = ((const float4*)(x + (size_t)tok * Dc))[t];
        ushort4_t o = { f2bf(v.x), f2bf(v.y), f2bf(v.z), f2bf(v.w) };
        *(ushort4_t*)(Xg + (size_t)row * Dc + t * 4) = o;
    }
}

// ---------- GEMM tile config ----------
#define BM 128
#define BN 64
#define BK 64
// LDS tile rows are 64 bf16 = 128B = 8 chunks of 16B.
// Physical chunk position = logical_chunk ^ (row & 7)  (bank-conflict swizzle).
// global_load_lds: lane -> row = base+(lane>>3), phys chunk = lane&7, so lane
// fetches global logical chunk (lane&7)^(row&7). 8x128B segments per inst.

__device__ inline void stage_rows128(const unsigned short* __restrict__ g0, size_t ld, int kk,
                                     unsigned short* lds, int w, int lane) {
    int rr = lane >> 3, cp = lane & 7;
#pragma unroll
    for (int j = 0; j < 4; j++) {
        int row = w * 32 + j * 8 + rr;
        int cl = cp ^ (row & 7);
        const char* g = (const char*)(g0 + (size_t)row * ld + kk + cl * 8);
        char* l = (char*)lds + (size_t)(w * 32 + j * 8) * 128;
        gload_lds16(g, l);
    }
}

__device__ inline void stage_rows64(const unsigned short* __restrict__ g0, size_t ld, int kk,
                                    unsigned short* lds, int w, int lane) {
    int rr = lane >> 3, cp = lane & 7;
#pragma unroll
    for (int j = 0; j < 2; j++) {
        int row = w * 16 + j * 8 + rr;
        int cl = cp ^ (row & 7);
        const char* g = (const char*)(g0 + (size_t)row * ld + kk + cl * 8);
        char* l = (char*)lds + (size_t)(w * 16 + j * 8) * 128;
        gload_lds16(g, l);
    }
}

// GEMM1: hidden[m, n] = gelu( sum_d Xg[m,d] * keys[e][n,d] ),  K=1024, N=2048
// 128x64 tile -> 32 x-blocks x 40 tiles = 1280 blocks, 24KB LDS -> 6 blocks/CU
__global__ __launch_bounds__(256, 4) void gemm1_kernel(
    const unsigned short* __restrict__ Xg,      // [Pc+PADROWS, 1024] bf16
    const unsigned short* __restrict__ keysb,   // [E, 2048, 1024] bf16
    const int* __restrict__ counts, const int* __restrict__ offs,
    const int* __restrict__ tile_e, const int* __restrict__ tile_m0,
    const int* __restrict__ n_tiles,
    unsigned short* __restrict__ hidden)        // [Pc+PADROWS, 2048] bf16
{
    int ty = blockIdx.y;
    if (ty >= *n_tiles) return;
    int e = tile_e[ty], m0 = tile_m0[ty];
    int cnt = counts[e], moff = offs[e];
    int n0 = blockIdx.x * BN;
    const unsigned short* Ag = Xg + (size_t)(moff + m0) * Dc;
    const unsigned short* Bg = keysb + (size_t)e * Hc * Dc + (size_t)n0 * Dc;

    __shared__ unsigned short As[BM * BK];
    __shared__ unsigned short Bs[BN * BK];

    int t = threadIdx.x;
    int lane = t & 63, w = t >> 6;
    int Mq = (w & 1) * 64, Nq = (w >> 1) * 32;
    int l15 = lane & 15, l4 = lane >> 4;
    int rx = l15 & 7;   // row-dependent swizzle factor for fragment reads

    floatx4 acc[4][2];
#pragma unroll
    for (int i = 0; i < 4; i++)
#pragma unroll
        for (int j = 0; j < 2; j++) acc[i][j] = (floatx4){0.f, 0.f, 0.f, 0.f};

    for (int kk = 0; kk < Dc; kk += BK) {
        __syncthreads();
        stage_rows128(Ag, Dc, kk, As, w, lane);
        stage_rows64(Bg, Dc, kk, Bs, w, lane);
        __syncthreads();
#pragma unroll
        for (int s = 0; s < 2; s++) {
            bf16x8 af[4], bfr[2];
#pragma unroll
            for (int mi = 0; mi < 4; mi++)
                af[mi] = *(const bf16x8*)(As + (Mq + mi * 16 + l15) * BK + (((s * 4 + l4) ^ rx) * 8));
#pragma unroll
            for (int ni = 0; ni < 2; ni++)
                bfr[ni] = *(const bf16x8*)(Bs + (Nq + ni * 16 + l15) * BK + (((s * 4 + l4) ^ rx) * 8));
#pragma unroll
            for (int mi = 0; mi < 4; mi++)
#pragma unroll
                for (int ni = 0; ni < 2; ni++)
                    acc[mi][ni] = __builtin_amdgcn_mfma_f32_16x16x32_bf16(af[mi], bfr[ni], acc[mi][ni], 0, 0, 0);
        }
    }

#pragma unroll
    for (int mi = 0; mi < 4; mi++) {
#pragma unroll
        for (int r = 0; r < 4; r++) {
            int mloc = Mq + mi * 16 + l4 * 4 + r;
            int gm = m0 + mloc;
            if (gm < cnt) {
                size_t rowbase = (size_t)(moff + gm) * Hc + n0;
#pragma unroll
                for (int ni = 0; ni < 2; ni++) {
                    float g = gelu_fast(acc[mi][ni][r]);
                    hidden[rowbase + Nq + ni * 16 + l15] = f2bf(g);
                }
            }
        }
    }
}

// GEMM2: out[token, n] += w * sum_h hidden[m,h] * values[e][n,h]
// split-K: blockIdx.z selects K-half (2 x 1024); 128x64 tile -> 16x40x2 = 1280 blocks
__global__ __launch_bounds__(256, 4) void gemm2_kernel(
    const unsigned short* __restrict__ hidden,  // [Pc+PADROWS, 2048] bf16
    const unsigned short* __restrict__ valsb,   // [E, 1024, 2048] bf16
    const int* __restrict__ counts, const int* __restrict__ offs,
    const int* __restrict__ tile_e, const int* __restrict__ tile_m0,
    const int* __restrict__ n_tiles,
    const int* __restrict__ job_token, const float* __restrict__ job_w,
    float* __restrict__ out)
{
    int ty = blockIdx.y;
    if (ty >= *n_tiles) return;
    int e = tile_e[ty], m0 = tile_m0[ty];
    int cnt = counts[e], moff = offs[e];
    int n0 = blockIdx.x * BN;
    int k_begin = blockIdx.z * (Hc / 2);
    int k_end = k_begin + (Hc / 2);
    const unsigned short* Ag = hidden + (size_t)(moff + m0) * Hc;
    const unsigned short* Bg = valsb + (size_t)e * Dc * Hc + (size_t)n0 * Hc;

    __shared__ unsigned short As[BM * BK];
    __shared__ unsigned short Bs[BN * BK];

    int t = threadIdx.x;
    int lane = t & 63, w = t >> 6;
    int Mq = (w & 1) * 64, Nq = (w >> 1) * 32;
    int l15 = lane & 15, l4 = lane >> 4;
    int rx = l15 & 7;

    floatx4 acc[4][2];
#pragma unroll
    for (int i = 0; i < 4; i++)
#pragma unroll
        for (int j = 0; j < 2; j++) acc[i][j] = (floatx4){0.f, 0.f, 0.f, 0.f};

    for (int kk = k_begin; kk < k_end; kk += BK) {
        __syncthreads();
        stage_rows128(Ag, Hc, kk, As, w, lane);
        stage_rows64(Bg, Hc, kk, Bs, w, lane);
        __syncthreads();
#pragma unroll
        for (int s = 0; s < 2; s++) {
            bf16x8 af[4], bfr[2];
#pragma unroll
            for (int mi = 0; mi < 4; mi++)
                af[mi] = *(const bf16x8*)(As + (Mq + mi * 16 + l15) * BK + (((s * 4 + l4) ^ rx) * 8));
#pragma unroll
            for (int ni = 0; ni < 2; ni++)
                bfr[ni] = *(const bf16x8*)(Bs + (Nq + ni * 16 + l15) * BK + (((s * 4 + l4) ^ rx) * 8));
#pragma unroll
            for (int mi = 0; mi < 4; mi++)
#pragma unroll
                for (int ni = 0; ni < 2; ni++)
                    acc[mi][ni] = __builtin_amdgcn_mfma_f32_16x16x32_bf16(af[mi], bfr[ni], acc[mi][ni], 0, 0, 0);
        }
    }

#pragma unroll
    for (int mi = 0; mi < 4; mi++) {
#pragma unroll
        for (int r = 0; r < 4; r++) {
            int mloc = Mq + mi * 16 + l4 * 4 + r;
            int gm = m0 + mloc;
            if (gm < cnt) {
                int tok = job_token[moff + gm];
                float wgt = job_w[moff + gm];
                float* orow = out + (size_t)tok * Dc + n0;
#pragma unroll
                for (int ni = 0; ni < 2; ni++) {
                    atomicAdd(orow + Nq + ni * 16 + l15, wgt * acc[mi][ni][r]);
                }
            }
        }
    }
}

// ---------- workspace layout (bytes) ----------
// counts     @ 0        (32)
// offs       @ 64       (36 -> pad to 128)
// tile_e     @ 128      (160 -> pad 192)
// tile_m0    @ 320      (160 -> pad 192)
// n_tiles    @ 512      (4 -> pad 128)
// job_token  @ 640      (16384)
// job_w      @ 17024    (16384)
// Xg         @ 33408    ((4096+128)*1024*2 = 8650752)
// keysb      @ 8684160  (33554432)
// valsb      @ 42238592 (33554432)
// hidden     @ 75793024 ((4096+128)*2048*2 = 17301504) -> total 93094528 B

extern "C" void kernel_launch(void* const* d_in, const int* in_sizes, int n_in,
                              void* d_out, int out_size, void* d_ws, size_t ws_size,
                              hipStream_t stream) {
    const float* x      = (const float*)d_in[0];
    const float* keys   = (const float*)d_in[1];
    const float* values = (const float*)d_in[2];
    const int*   eidx   = (const int*)d_in[3];
    const float* ew     = (const float*)d_in[4];
    float* out = (float*)d_out;
    char* ws = (char*)d_ws;

    int*   counts    = (int*)(ws + 0);
    int*   offs      = (int*)(ws + 64);
    int*   tile_e    = (int*)(ws + 128);
    int*   tile_m0   = (int*)(ws + 320);
    int*   n_tiles   = (int*)(ws + 512);
    int*   job_token = (int*)(ws + 640);
    float* job_w     = (float*)(ws + 17024);
    unsigned short* Xg     = (unsigned short*)(ws + 33408);
    unsigned short* keysb  = (unsigned short*)(ws + 8684160);
    unsigned short* valsb  = (unsigned short*)(ws + 42238592);
    unsigned short* hidden = (unsigned short*)(ws + 75793024);

    hipMemsetAsync(d_out, 0, (size_t)out_size * 4, stream);   // fp32 accum target

    bucket_kernel<<<1, 256, 0, stream>>>(eidx, ew, counts, offs, tile_e, tile_m0,
                                         n_tiles, job_token, job_w);

    prep_kernel<<<PREP_BLOCKS, 256, 0, stream>>>(keys, values, keysb, valsb,
                                                 x, job_token, Xg);

    gemm1_kernel<<<dim3(Hc / BN, MAXTILES, 1), 256, 0, stream>>>(
        Xg, keysb, counts, offs, tile_e, tile_m0, n_tiles, hidden);
    gemm2_kernel<<<dim3(Dc / BN, MAXTILES, 2), 256, 0, stream>>>(
        hidden, valsb, counts, offs, tile_e, tile_m0, n_tiles, job_token, job_w, out);
}